// Round 1
// 366.686 us; speedup vs baseline: 1.0814x; 1.0814x over previous
//
#include <hip/hip_runtime.h>

#define DD 512
#define DKk 100
#define NT 7          // ceil(100/16) column tiles
#define CHUNK 16
#define MAXN 208      // max padded N (200 -> 13 chunks * 16)
#define LDS_STRIDE 520  // shorts per staged row (+8 pad: 2-way banks, free)

typedef __attribute__((ext_vector_type(8))) short short8;
typedef __attribute__((ext_vector_type(4))) short short4v;
typedef __attribute__((ext_vector_type(4))) float f32x4;

struct AttendArgs {
  const float* feats[4];
  const float* wfeat[4];
  const float* wf[4];
  const float* bias[4];
  int   N[4];
  float coef[4];
};

// fp32 -> bf16 bits, round-to-nearest-even
__device__ __forceinline__ short f2bf(float x) {
  unsigned u = __builtin_bit_cast(unsigned, x);
  unsigned r = (u + 0x7fffu + ((u >> 16) & 1u)) >> 16;
  return (short)r;
}

__device__ __forceinline__ float bf2f(unsigned short s) {
  unsigned u = ((unsigned)s) << 16;
  return __builtin_bit_cast(float, u);
}

__device__ __forceinline__ float fast_tanh(float x) {
  const float e = __expf(2.0f * x);
  return 1.0f - 2.0f / (e + 1.0f);
}

// ---------------------------------------------------------------------------
// wprep v2 (R3): coalesced. Old version gathered w[d*100+col] with 400 B lane
// stride (fully uncoalesced). Now: stage 128 rows of w into LDS with linear
// coalesced loads, then emit MFMA-B-fragment order from LDS.
// grid: 4 a's x 4 quarters (d in [qtr*128, qtr*128+128)), 256 threads.
// Layout (unchanged): wfrag[((a*7+t)*16+ks)*512 + lane*8 + j] = bf16(w[d][col]),
// d = ks*32 + (lane>>4)*8 + j, col = t*16 + (lane&15). Zero past col>=100.
// ---------------------------------------------------------------------------
__global__ void wprep_kernel(AttendArgs args, unsigned short* __restrict__ wfrag) {
  const int a   = blockIdx.x >> 2;
  const int qtr = blockIdx.x & 3;
  const int tid = threadIdx.x;
  const int lane = tid & 63;
  const int m = lane & 15;
  const int q = lane >> 4;
  const int sub = tid >> 6;             // 0..3
  const int ks  = qtr * 4 + sub;
  __shared__ float wbuf[128 * DKk];     // 51,200 B
  const float* __restrict__ w = args.wfeat[a] + (size_t)qtr * 128 * DKk;
  #pragma unroll
  for (int i = 0; i < 50; ++i)          // 128*100 = 50*256 floats, coalesced
    wbuf[i * 256 + tid] = w[i * 256 + tid];
  __syncthreads();
  #pragma unroll
  for (int t = 0; t < NT; ++t) {
    const int col = t * 16 + m;
    short8 v;
    #pragma unroll
    for (int j = 0; j < 8; ++j) {
      const int drel = sub * 32 + q * 8 + j;     // d - qtr*128
      v[j] = (col < DKk) ? f2bf(wbuf[drel * DKk + col]) : (short)0;
    }
    unsigned short* dst = wfrag + (size_t)(((a * NT + t) * 16 + ks) * 512) + lane * 8;
    *reinterpret_cast<short8*>(dst) = v;
  }
}

// ---------------------------------------------------------------------------
// Fused per-(a,b) kernel, R3: single-pass online accumulation.
// Scores are bounded (tanh in (-1,1), |wf|_1 ~ 4, b=0) => softmax needs no
// max-subtraction: out = (sum_n e^{s_n} feats_n) / (sum_n e^{s_n}).
// Per chunk c (2 barriers):
//   stage(c)->prefetch(c+1)->B1-> [waves0-6: MFMA(c)+shfl->sc_part]
//                                 [all waves: accumulate chunk c-1 from the
//                                  OTHER LDS buffer into partial[8][512]]
//                             ->B2
// Thread (wave h, lane g) owns cols 8g..8g+7, rows h and h+8 of each chunk;
// accumulator lives in LDS (no persistent VGPR growth -> keep 2 blocks/CU).
// This deletes the old phase-2: ~200 dependent scalar L3 loads per thread.
// ---------------------------------------------------------------------------
__global__ __launch_bounds__(512, 2)
void fused_kernel(AttendArgs args, const unsigned short* __restrict__ wfrag,
                  float* __restrict__ out) {
  const int a = blockIdx.x & 3;        // interleave a for load balance (a=3 short)
  const int b = blockIdx.x >> 2;
  const int tid = threadIdx.x;
  const int lane = tid & 63;
  const int wave = tid >> 6;           // = col tile t (0..6 MFMA; all 8 accumulate)
  const int m = lane & 15;
  const int q = lane >> 4;
  const int N = args.N[a];
  const float* __restrict__ feats = args.feats[a] + (size_t)b * (size_t)N * DD;
  const float* __restrict__ wfp = args.wf[a];
  const float* __restrict__ bias = args.bias[a];

  __shared__ __align__(16) unsigned short f_lds[2][CHUNK][LDS_STRIDE]; // 33,280 B
  __shared__ float sc_part[8][MAXN];                                   //  6,656 B
  __shared__ __align__(16) float partial[8][DD];                       // 16,384 B
  __shared__ float red[512];                                           //  2,048 B
  // total 58,368 B -> 2 blocks/CU fits in 160 KiB

  // --- B fragments for this wave's tile (coalesced, pre-formatted) ---
  short8 bfrag[16];
  float wfv = 0.f;
  if (wave < NT) {
    const int col = wave * 16 + m;
    wfv = (col < DKk) ? wfp[col] : 0.f;
    const unsigned short* src = wfrag + (size_t)((a * NT + wave) * 16) * 512 + lane * 8;
    #pragma unroll
    for (int ks = 0; ks < 16; ++ks)
      bfrag[ks] = *reinterpret_cast<const short8*>(src + (size_t)ks * 512);
  } else {
    #pragma unroll
    for (int ks = 0; ks < 16; ++ks) bfrag[ks] = short8(0);
  }

  // --- prefill: sc_part[7] holds bias (read as the 8th partial); zero partial
  if (tid < MAXN) sc_part[7][tid] = (tid < N) ? bias[tid] : 0.f;
  {
    const f32x4 z = {0.f, 0.f, 0.f, 0.f};
    *reinterpret_cast<f32x4*>(&partial[wave][lane * 8])     = z;
    *reinterpret_cast<f32x4*>(&partial[wave][lane * 8 + 4]) = z;
  }

  const int nchunks = (N + CHUNK - 1) / CHUNK;

  // accumulate chunk whose rows start at n0, staged in f_lds[pb].
  // Rows >= N are zero-staged, so their (e=exp(0)=1) contribution is 0 — no guard.
  auto accum = [&](int pb, int n0) {
    float* pp = &partial[wave][lane * 8];
    f32x4 lo = *reinterpret_cast<f32x4*>(pp);
    f32x4 hi = *reinterpret_cast<f32x4*>(pp + 4);
    {
      const int n1 = n0 + wave;
      const float s1 = sc_part[0][n1] + sc_part[1][n1] + sc_part[2][n1] + sc_part[3][n1]
                     + sc_part[4][n1] + sc_part[5][n1] + sc_part[6][n1] + sc_part[7][n1];
      const float e1 = __expf(s1);
      const short8 f1 = *reinterpret_cast<const short8*>(&f_lds[pb][wave][lane * 8]);
      #pragma unroll
      for (int j = 0; j < 4; ++j) {
        lo[j] = fmaf(e1, bf2f((unsigned short)f1[j]),     lo[j]);
        hi[j] = fmaf(e1, bf2f((unsigned short)f1[j + 4]), hi[j]);
      }
    }
    {
      const int n2 = n0 + wave + 8;
      const float s2 = sc_part[0][n2] + sc_part[1][n2] + sc_part[2][n2] + sc_part[3][n2]
                     + sc_part[4][n2] + sc_part[5][n2] + sc_part[6][n2] + sc_part[7][n2];
      const float e2 = __expf(s2);
      const short8 f2 = *reinterpret_cast<const short8*>(&f_lds[pb][wave + 8][lane * 8]);
      #pragma unroll
      for (int j = 0; j < 4; ++j) {
        lo[j] = fmaf(e2, bf2f((unsigned short)f2[j]),     lo[j]);
        hi[j] = fmaf(e2, bf2f((unsigned short)f2[j + 4]), hi[j]);
      }
    }
    *reinterpret_cast<f32x4*>(pp)     = lo;
    *reinterpret_cast<f32x4*>(pp + 4) = hi;
  };

  // --- prefetch chunk 0 into registers (4 float4 / thread = 16 rows x 512) ---
  float4 pf[4];
  #pragma unroll
  for (int it = 0; it < 4; ++it) {
    const int idx = tid + it * 512;
    const int row = idx >> 7;
    const int c4 = idx & 127;
    pf[it] = (row < N)
      ? *reinterpret_cast<const float4*>(feats + (size_t)row * DD + (c4 << 2))
      : make_float4(0.f, 0.f, 0.f, 0.f);
  }

  for (int c = 0; c < nchunks; ++c) {
    const int bufc = c & 1;
    // stage regs (chunk c) -> bf16 LDS
    #pragma unroll
    for (int it = 0; it < 4; ++it) {
      const int idx = tid + it * 512;
      const int row = idx >> 7;
      const int c4 = idx & 127;
      short4v pk = { f2bf(pf[it].x), f2bf(pf[it].y), f2bf(pf[it].z), f2bf(pf[it].w) };
      *reinterpret_cast<short4v*>(&f_lds[bufc][row][c4 << 2]) = pk;
    }
    // issue prefetch of chunk c+1 (reg loads: no vmcnt drain at barrier; they
    // stay in flight across B1 + compute + B2)
    if (c + 1 < nchunks) {
      const int n0n = (c + 1) * CHUNK;
      #pragma unroll
      for (int it = 0; it < 4; ++it) {
        const int idx = tid + it * 512;
        const int row = n0n + (idx >> 7);
        const int c4 = idx & 127;
        pf[it] = (row < N)
          ? *reinterpret_cast<const float4*>(feats + (size_t)row * DD + (c4 << 2))
          : make_float4(0.f, 0.f, 0.f, 0.f);
      }
    }
    __syncthreads();  // B1: staging of c visible to MFMA readers

    if (wave < NT) {
      f32x4 acc = {0.f, 0.f, 0.f, 0.f};
      #pragma unroll
      for (int ks = 0; ks < 16; ++ks) {
        const short8 af = *reinterpret_cast<const short8*>(&f_lds[bufc][m][ks * 32 + q * 8]);
        acc = __builtin_amdgcn_mfma_f32_16x16x32_bf16(af, bfrag[ks], acc, 0, 0, 0);
      }
      float part[4];
      #pragma unroll
      for (int r = 0; r < 4; ++r) part[r] = fast_tanh(acc[r]) * wfv;
      #pragma unroll
      for (int mask = 1; mask <= 8; mask <<= 1) {
        #pragma unroll
        for (int r = 0; r < 4; ++r) part[r] += __shfl_xor(part[r], mask, 64);
      }
      if (m == 0) {
        #pragma unroll
        for (int r = 0; r < 4; ++r) sc_part[wave][c * 16 + q * 4 + r] = part[r];
      }
    }
    // online accumulate of the PREVIOUS chunk (other buffer; overlaps MFMA and
    // the in-flight prefetch of c+1)
    if (c > 0) accum(bufc ^ 1, (c - 1) * CHUNK);
    __syncthreads();  // B2: accumulate reads done before next stage overwrites
  }

  // tail: accumulate the last chunk (sc_part visible via loop-end B2)
  accum((nchunks - 1) & 1, (nchunks - 1) * CHUNK);
  __syncthreads();

  // --- denominator: sum_n exp(s_n), no max pass (scores bounded ~|8|) ---
  float e = 0.f;
  if (tid < N) {
    const float sval = sc_part[0][tid] + sc_part[1][tid] + sc_part[2][tid] + sc_part[3][tid]
                     + sc_part[4][tid] + sc_part[5][tid] + sc_part[6][tid] + sc_part[7][tid];
    e = __expf(sval);
  }
  red[tid] = e;
  __syncthreads();
  for (int s = 256; s > 0; s >>= 1) {
    if (tid < s) red[tid] += red[tid + s];
    __syncthreads();
  }
  const float scale = args.coef[a] / red[0];

  // --- cross-h reduce of the value accumulator, one atomic per column ---
  const float val = partial[0][tid] + partial[1][tid] + partial[2][tid] + partial[3][tid]
                  + partial[4][tid] + partial[5][tid] + partial[6][tid] + partial[7][tid];
  atomicAdd(&out[(size_t)b * DD + tid], val * scale);
}

extern "C" void kernel_launch(void* const* d_in, const int* in_sizes, int n_in,
                              void* d_out, int out_size, void* d_ws, size_t ws_size,
                              hipStream_t stream) {
  AttendArgs args;
  args.feats[0] = (const float*)d_in[0];
  args.wfeat[0] = (const float*)d_in[4];
  args.wf[0]    = (const float*)d_in[6];          // vec_first=False: wf = w_p[:100]
  args.bias[0]  = (const float*)d_in[7];
  args.N[0] = 196; args.coef[0] = 1.0f;

  args.feats[1] = (const float*)d_in[1];
  args.wfeat[1] = (const float*)d_in[9];
  args.wf[1]    = (const float*)d_in[10] + 100;   // vec_first=True: wf = w_p[100:]
  args.bias[1]  = (const float*)d_in[11];
  args.N[1] = 200; args.coef[1] = 1.0f;

  args.feats[2] = (const float*)d_in[2];
  args.wfeat[2] = (const float*)d_in[13];
  args.wf[2]    = (const float*)d_in[14] + 100;
  args.bias[2]  = (const float*)d_in[15];
  args.N[2] = 200; args.coef[2] = 0.5f;

  args.feats[3] = (const float*)d_in[3];
  args.wfeat[3] = (const float*)d_in[17];
  args.wf[3]    = (const float*)d_in[18] + 100;
  args.bias[3]  = (const float*)d_in[19];
  args.N[3] = 50;  args.coef[3] = 0.5f;

  unsigned short* wfrag = (unsigned short*)d_ws;  // 4*7*16*512*2 = 458,752 B

  hipMemsetAsync(d_out, 0, (size_t)out_size * sizeof(float), stream);
  wprep_kernel<<<dim3(16), dim3(256), 0, stream>>>(args, wfrag);
  fused_kernel<<<dim3(4 * 256), dim3(512), 0, stream>>>(args, wfrag, (float*)d_out);
}